// Round 5
// baseline (182.050 us; speedup 1.0000x reference)
//
#include <hip/hip_runtime.h>
#include <math.h>

#define T_END_F 100.0f
#define N_TAB 4096
#define HID 128
#define N_MC_TOTAL 92160  // 15 * 16 * 384
#define TF_HALF 46080u

// build: 512 blocks x 256 threads; 8 entries/block; thread = (unit k, entry
// half) -> 4 entries/thread, full weight column W[:,k] burst-loaded into
// 128 registers (kills the per-j-group cold-L2 latency chain).
#define B_EV 8
#define B_THREADS 256
#define NBLK_BUILD (N_TAB / B_EV)   // 512

// fused: 360 blocks x 512 threads (unchanged from R4).
#define FUSED_BLOCKS 360
#define F_THREADS 512

// ---------- math helpers ----------
__device__ __forceinline__ float softplusf(float z){
  return fmaxf(z, 0.0f) + log1pf(expf(-fabsf(z)));
}

__device__ __forceinline__ unsigned rotl32(unsigned x, unsigned d){
  return (x << d) | (x >> (32u - d));
}

// Bit-exact JAX threefry2x32 uniform for key(42), total count 92160.
__device__ float threefry_u01(unsigned idx){
  unsigned i0, i1;
  bool second = idx >= TF_HALF;
  if (second){ i0 = idx - TF_HALF; i1 = idx; }
  else       { i0 = idx;           i1 = idx + TF_HALF; }
  const unsigned ks0 = 0u;
  const unsigned ks1 = 42u;
  const unsigned ks2 = 0x1BD11BDAu ^ ks0 ^ ks1;
  unsigned x0 = i0 + ks0;
  unsigned x1 = i1 + ks1;
#define TF_R(r) { x0 += x1; x1 = rotl32(x1, (r)); x1 ^= x0; }
  TF_R(13) TF_R(15) TF_R(26) TF_R(6)
  x0 += ks1; x1 += ks2 + 1u;
  TF_R(17) TF_R(29) TF_R(16) TF_R(24)
  x0 += ks2; x1 += ks0 + 2u;
  TF_R(13) TF_R(15) TF_R(26) TF_R(6)
  x0 += ks0; x1 += ks1 + 3u;
  TF_R(17) TF_R(29) TF_R(16) TF_R(24)
  x0 += ks1; x1 += ks2 + 4u;
  TF_R(13) TF_R(15) TF_R(26) TF_R(6)
  x0 += ks2; x1 += ks0 + 5u;
#undef TF_R
  unsigned bits = second ? x1 : x0;
  unsigned fb = (bits >> 9) | 0x3F800000u;
  return __uint_as_float(fb) - 1.0f;
}

// LDS-resident table lookup
#define TABLE_LDS(xval) ({                                        \
  float _pos = (xval) * ((float)(N_TAB - 1) / T_END_F);           \
  int _i = (int)_pos;                                             \
  if (_i < 0) _i = 0;                                             \
  if (_i > N_TAB - 2) _i = N_TAB - 2;                             \
  float _fr = _pos - (float)_i;                                   \
  float _a = sm_tab[_i];                                          \
  float _b = sm_tab[_i + 1];                                      \
  fmaf(_fr, _b - _a, _a); })

// Column-resident dense layer for 4 entries. The full column W[:,k] is
// burst-loaded into registers FIRST (128 independent coalesced loads ->
// one pipelined cold-miss latency instead of 32 serialized ones), then all
// fmafs run register-resident. Per-(entry,unit) fmaf chain is the same
// ascending-j single-accumulator order as all previous versions ->
// bit-identical results. All indices compile-time (full unroll) -> no scratch.
__device__ __forceinline__ void dense_col(
    const float (*__restrict__ hin)[HID], float (*__restrict__ hout)[HID],
    const float* __restrict__ W, const float* __restrict__ bv,
    int k, int e0)
{
  float w[HID];
#pragma unroll
  for (int j = 0; j < HID; ++j)
    w[j] = W[j * HID + k];          // coalesced (lane-consecutive k)

  float acc0 = bv[k];
  float acc1 = acc0, acc2 = acc0, acc3 = acc0;
#pragma unroll
  for (int j = 0; j < HID; j += 4){
    float4 h0 = *(const float4*)&hin[e0 + 0][j];   // wave-uniform LDS broadcast
    float4 h1 = *(const float4*)&hin[e0 + 1][j];
    float4 h2 = *(const float4*)&hin[e0 + 2][j];
    float4 h3 = *(const float4*)&hin[e0 + 3][j];
    acc0 = fmaf(h0.x, w[j+0], acc0);  acc1 = fmaf(h1.x, w[j+0], acc1);
    acc2 = fmaf(h2.x, w[j+0], acc2);  acc3 = fmaf(h3.x, w[j+0], acc3);
    acc0 = fmaf(h0.y, w[j+1], acc0);  acc1 = fmaf(h1.y, w[j+1], acc1);
    acc2 = fmaf(h2.y, w[j+1], acc2);  acc3 = fmaf(h3.y, w[j+1], acc3);
    acc0 = fmaf(h0.z, w[j+2], acc0);  acc1 = fmaf(h1.z, w[j+2], acc1);
    acc2 = fmaf(h2.z, w[j+2], acc2);  acc3 = fmaf(h3.z, w[j+2], acc3);
    acc0 = fmaf(h0.w, w[j+3], acc0);  acc1 = fmaf(h1.w, w[j+3], acc1);
    acc2 = fmaf(h2.w, w[j+3], acc2);  acc3 = fmaf(h3.w, w[j+3], acc3);
  }
  hout[e0 + 0][k] = tanhf(acc0);
  hout[e0 + 1][k] = tanhf(acc1);
  hout[e0 + 2][k] = tanhf(acc2);
  hout[e0 + 3][k] = tanhf(acc3);
}

// ---------- table build: 512 blocks x 256 threads ----------
__global__ __launch_bounds__(B_THREADS, 2) void build_table_kernel(
    const float* __restrict__ W1, const float* __restrict__ b1v,
    const float* __restrict__ W2, const float* __restrict__ b2v,
    const float* __restrict__ W3, const float* __restrict__ b3v,
    const float* __restrict__ W4, const float* __restrict__ b4v,
    float* __restrict__ tab)
{
  __shared__ float hA[B_EV][HID];   // 4 KB
  __shared__ float hB[B_EV][HID];   // 4 KB
  const int tid  = threadIdx.x;
  const int k    = tid & 127;      // hidden unit
  const int half = tid >> 7;       // 0/1: which 4-entry group
  const int e0   = half * 4;
  const int base = blockIdx.x * B_EV;
  const float dt = T_END_F / (float)(N_TAB - 1);

  // layer 1: scalar -> 128 (identical per-entry expression)
  {
    float w = W1[k], b = b1v[k];
#pragma unroll
    for (int q = 0; q < 4; ++q){
      float x = (float)(base + e0 + q) * dt;
      hA[e0 + q][k] = tanhf(fmaf(x, w, b));
    }
  }
  __syncthreads();

  dense_col(hA, hB, W2, b2v, k, e0);   // layer 2
  __syncthreads();
  dense_col(hB, hA, W3, b3v, k, e0);   // layer 3
  __syncthreads();

  // layer 4: 128 -> 1, softplus. Wave wv owns entries wv*2, wv*2+1;
  // identical expression + xor-tree -> bit-identical table values.
  {
    const int wv   = tid >> 6;       // 0..3
    const int lane = tid & 63;
    float wa = W4[lane], wb = W4[lane + 64];
    float b4s = b4v[0];
#pragma unroll
    for (int r = 0; r < 2; ++r){
      int e = wv * 2 + r;
      float p = hA[e][lane] * wa + hA[e][lane + 64] * wb;
      p += __shfl_xor(p, 32);
      p += __shfl_xor(p, 16);
      p += __shfl_xor(p, 8);
      p += __shfl_xor(p, 4);
      p += __shfl_xor(p, 2);
      p += __shfl_xor(p, 1);
      if (lane == 0) tab[base + e] = softplusf(p + b4s);
    }
  }
}

// ---------- fused: pairs log-sum + MC integral (unchanged from R4) ----------
__global__ __launch_bounds__(F_THREADS) void fused_kernel(
    const float* __restrict__ t,        // [16][384]
    const int* __restrict__ seq_lens,   // [16]
    const float* __restrict__ bg,
    const float* __restrict__ tab,
    float* __restrict__ partials)       // [2*FUSED_BLOCKS]: logs then mc
{
  __shared__ float sm_tab[N_TAB];       // 16 KB
  __shared__ float redL[8], redM[8];

  const int tid  = threadIdx.x;
  const int lane = tid & 63;
  const int wv   = tid >> 6;           // 0..7
  const float bgv = bg[0];

  // stage table to LDS: 4096 floats / 512 threads = 2 float4 each
  {
    const float4* g4 = (const float4*)tab;
    float4* s4 = (float4*)sm_tab;
#pragma unroll
    for (int q = 0; q < 2; ++q)
      s4[q * F_THREADS + tid] = g4[q * F_THREADS + tid];
  }
  __syncthreads();

  float logsum = 0.0f;   // only lane 0 accumulates
  float mcv    = 0.0f;

  // pairs: tasks gwave + kk*2880, kk = 0..2 (task < 6144)
  const int gwave = blockIdx.x * 8 + wv;   // 0..2879
#pragma unroll
  for (int kk = 0; kk < 3; ++kk){
    unsigned task = (unsigned)gwave + (unsigned)kk * 2880u;
    if (task < 6144u){
      unsigned b = task / 384u;
      int i = (int)(task - b * 384u);
      if (i < seq_lens[b]){
        const float* tb = t + b * 384u;
        float ti = tb[i];
        float s = 0.0f;
        for (int j = lane; j < i; j += 64)
          s += TABLE_LDS(ti - tb[j]);
        s += __shfl_xor(s, 32);
        s += __shfl_xor(s, 16);
        s += __shfl_xor(s, 8);
        s += __shfl_xor(s, 4);
        s += __shfl_xor(s, 2);
        s += __shfl_xor(s, 1);
        if (lane == 0) logsum += logf(s + bgv);
      }
    }
  }

  // Monte Carlo sample: value is a function of idx only -> bit-identical
  {
    int idx = blockIdx.x * F_THREADS + tid;
    if (idx < N_MC_TOTAL){
      int l = idx % 384;
      int b = (idx / 384) & 15;
      if (l < seq_lens[b]){
        float tv = t[b * 384 + l];
        float dl = T_END_F - tv;
        float u  = threefry_u01((unsigned)idx);
        mcv = (TABLE_LDS(u * dl) + 1e-10f) * dl;
      }
    }
  }
  mcv += __shfl_xor(mcv, 32);
  mcv += __shfl_xor(mcv, 16);
  mcv += __shfl_xor(mcv, 8);
  mcv += __shfl_xor(mcv, 4);
  mcv += __shfl_xor(mcv, 2);
  mcv += __shfl_xor(mcv, 1);

  if (lane == 0){ redL[wv] = logsum; redM[wv] = mcv; }
  __syncthreads();
  if (tid == 0){
    float bl = 0.0f, bm = 0.0f;
#pragma unroll
    for (int q = 0; q < 8; ++q){ bl += redL[q]; bm += redM[q]; }
    partials[blockIdx.x]                = bl;
    partials[FUSED_BLOCKS + blockIdx.x] = bm;
  }
}

// ---------- finalize: deterministic 16-residue reduction, 1 wave ----------
__global__ __launch_bounds__(64) void finalize_kernel(
    const float* __restrict__ partials,
    const float* __restrict__ bg,
    float* __restrict__ out)
{
  __shared__ float sl16[16], sm16[16];
  const int lane = threadIdx.x;
  if (lane < 16){
    float a = 0.0f, b = 0.0f;
    for (int p = lane; p < FUSED_BLOCKS; p += 16){
      a += partials[p];
      b += partials[FUSED_BLOCKS + p];
    }
    sl16[lane] = a;
    sm16[lane] = b;
  }
  __syncthreads();
  if (lane == 0){
    float sl = 0.0f, sm = 0.0f;
#pragma unroll
    for (int q = 0; q < 16; ++q){ sl += sl16[q]; sm += sm16[q]; }
    float bgv = bg[0];
    float lamb_ints_total = sm * (1.0f / 15.0f) + 16.0f * T_END_F * bgv;
    out[0] = -(sl - lamb_ints_total) / 16.0f;
  }
}

extern "C" void kernel_launch(void* const* d_in, const int* in_sizes, int n_in,
                              void* d_out, int out_size, void* d_ws, size_t ws_size,
                              hipStream_t stream)
{
  const float* seq_pads = (const float*)d_in[0];
  const int*   seq_lens = (const int*)d_in[1];
  const float* bg       = (const float*)d_in[2];
  const float* W1 = (const float*)d_in[3];
  const float* b1 = (const float*)d_in[4];
  const float* W2 = (const float*)d_in[5];
  const float* b2 = (const float*)d_in[6];
  const float* W3 = (const float*)d_in[7];
  const float* b3 = (const float*)d_in[8];
  const float* W4 = (const float*)d_in[9];
  const float* b4 = (const float*)d_in[10];
  float* out = (float*)d_out;

  float* tab      = (float*)d_ws;          // N_TAB floats
  float* partials = tab + N_TAB;           // 2*FUSED_BLOCKS floats

  build_table_kernel<<<NBLK_BUILD, B_THREADS, 0, stream>>>(
      W1, b1, W2, b2, W3, b3, W4, b4, tab);
  fused_kernel<<<FUSED_BLOCKS, F_THREADS, 0, stream>>>(
      seq_pads, seq_lens, bg, tab, partials);
  finalize_kernel<<<1, 64, 0, stream>>>(partials, bg, out);
}

// Round 6
// 111.258 us; speedup vs baseline: 1.6363x; 1.6363x over previous
//
#include <hip/hip_runtime.h>
#include <math.h>

#define T_END_F 100.0f
#define N_TAB 4096
#define HID 128
#define N_MC_TOTAL 92160  // 15 * 16 * 384
#define TF_HALF 46080u

// build: 512 blocks x 256 threads; 8 entries/block, 4 entries/thread.
// Weight column consumed in 4 chunks of 32 registers, double-buffered
// prefetch -> bounded live range (no spill), ~1 exposed cold-miss per layer.
#define B_EV 8
#define B_THREADS 256
#define NBLK_BUILD (N_TAB / B_EV)   // 512

// fused: 360 blocks x 512 threads (unchanged from R4, measured good).
#define FUSED_BLOCKS 360
#define F_THREADS 512

// ---------- math helpers ----------
__device__ __forceinline__ float softplusf(float z){
  return fmaxf(z, 0.0f) + log1pf(expf(-fabsf(z)));
}

__device__ __forceinline__ unsigned rotl32(unsigned x, unsigned d){
  return (x << d) | (x >> (32u - d));
}

// Bit-exact JAX threefry2x32 uniform for key(42), total count 92160.
__device__ float threefry_u01(unsigned idx){
  unsigned i0, i1;
  bool second = idx >= TF_HALF;
  if (second){ i0 = idx - TF_HALF; i1 = idx; }
  else       { i0 = idx;           i1 = idx + TF_HALF; }
  const unsigned ks0 = 0u;
  const unsigned ks1 = 42u;
  const unsigned ks2 = 0x1BD11BDAu ^ ks0 ^ ks1;
  unsigned x0 = i0 + ks0;
  unsigned x1 = i1 + ks1;
#define TF_R(r) { x0 += x1; x1 = rotl32(x1, (r)); x1 ^= x0; }
  TF_R(13) TF_R(15) TF_R(26) TF_R(6)
  x0 += ks1; x1 += ks2 + 1u;
  TF_R(17) TF_R(29) TF_R(16) TF_R(24)
  x0 += ks2; x1 += ks0 + 2u;
  TF_R(13) TF_R(15) TF_R(26) TF_R(6)
  x0 += ks0; x1 += ks1 + 3u;
  TF_R(17) TF_R(29) TF_R(16) TF_R(24)
  x0 += ks1; x1 += ks2 + 4u;
  TF_R(13) TF_R(15) TF_R(26) TF_R(6)
  x0 += ks2; x1 += ks0 + 5u;
#undef TF_R
  unsigned bits = second ? x1 : x0;
  unsigned fb = (bits >> 9) | 0x3F800000u;
  return __uint_as_float(fb) - 1.0f;
}

// LDS-resident table lookup
#define TABLE_LDS(xval) ({                                        \
  float _pos = (xval) * ((float)(N_TAB - 1) / T_END_F);           \
  int _i = (int)_pos;                                             \
  if (_i < 0) _i = 0;                                             \
  if (_i > N_TAB - 2) _i = N_TAB - 2;                             \
  float _fr = _pos - (float)_i;                                   \
  float _a = sm_tab[_i];                                          \
  float _b = sm_tab[_i + 1];                                      \
  fmaf(_fr, _b - _a, _a); })

// Dense layer for 4 entries. Weight column W[:,k] consumed in 4 chunks of
// 32 registers with double-buffered prefetch: chunk c+1's 32 independent
// coalesced loads are issued BEFORE chunk c's fmafs, so HBM cold-miss
// latency hides under compute; max live weight regs = 64 (no spill; R5's
// 128-live-reg version spilled -> 276 MB scratch writes).
// Per-(entry,unit) fmaf chain is the same ascending-j single-accumulator
// order as all previous versions -> bit-identical results. All indices
// compile-time after full unroll (rule #20).
__device__ __forceinline__ void dense4(
    const float (*__restrict__ hin)[HID], float (*__restrict__ hout)[HID],
    const float* __restrict__ W, const float* __restrict__ bv,
    int k, int e0)
{
  float wbuf[2][32];
  // preload chunk 0 (32 back-to-back independent loads -> one miss latency)
#pragma unroll
  for (int m = 0; m < 32; ++m)
    wbuf[0][m] = W[m * HID + k];

  float acc0 = bv[k];
  float acc1 = acc0, acc2 = acc0, acc3 = acc0;

#pragma unroll
  for (int c = 0; c < 4; ++c){
    // prefetch next chunk into the alternate buffer (issued before the
    // dependent fmafs below; compile-time buffer index since c is unrolled)
    if (c < 3){
#pragma unroll
      for (int m = 0; m < 32; ++m)
        wbuf[(c + 1) & 1][m] = W[((c + 1) * 32 + m) * HID + k];
    }
#pragma unroll
    for (int jj = 0; jj < 32; jj += 4){
      const int j = c * 32 + jj;
      float4 h0 = *(const float4*)&hin[e0 + 0][j];  // wave-uniform LDS reads
      float4 h1 = *(const float4*)&hin[e0 + 1][j];
      float4 h2 = *(const float4*)&hin[e0 + 2][j];
      float4 h3 = *(const float4*)&hin[e0 + 3][j];
      const float w0 = wbuf[c & 1][jj + 0];
      const float w1 = wbuf[c & 1][jj + 1];
      const float w2 = wbuf[c & 1][jj + 2];
      const float w3 = wbuf[c & 1][jj + 3];
      acc0 = fmaf(h0.x, w0, acc0);  acc1 = fmaf(h1.x, w0, acc1);
      acc2 = fmaf(h2.x, w0, acc2);  acc3 = fmaf(h3.x, w0, acc3);
      acc0 = fmaf(h0.y, w1, acc0);  acc1 = fmaf(h1.y, w1, acc1);
      acc2 = fmaf(h2.y, w1, acc2);  acc3 = fmaf(h3.y, w1, acc3);
      acc0 = fmaf(h0.z, w2, acc0);  acc1 = fmaf(h1.z, w2, acc1);
      acc2 = fmaf(h2.z, w2, acc2);  acc3 = fmaf(h3.z, w2, acc3);
      acc0 = fmaf(h0.w, w3, acc0);  acc1 = fmaf(h1.w, w3, acc1);
      acc2 = fmaf(h2.w, w3, acc2);  acc3 = fmaf(h3.w, w3, acc3);
    }
  }
  hout[e0 + 0][k] = tanhf(acc0);
  hout[e0 + 1][k] = tanhf(acc1);
  hout[e0 + 2][k] = tanhf(acc2);
  hout[e0 + 3][k] = tanhf(acc3);
}

// ---------- table build: 512 blocks x 256 threads ----------
__global__ __launch_bounds__(B_THREADS) void build_table_kernel(
    const float* __restrict__ W1, const float* __restrict__ b1v,
    const float* __restrict__ W2, const float* __restrict__ b2v,
    const float* __restrict__ W3, const float* __restrict__ b3v,
    const float* __restrict__ W4, const float* __restrict__ b4v,
    float* __restrict__ tab)
{
  __shared__ float hA[B_EV][HID];   // 4 KB
  __shared__ float hB[B_EV][HID];   // 4 KB
  const int tid  = threadIdx.x;
  const int k    = tid & 127;      // hidden unit
  const int half = tid >> 7;       // 0/1: which 4-entry group
  const int e0   = half * 4;
  const int base = blockIdx.x * B_EV;
  const float dt = T_END_F / (float)(N_TAB - 1);

  // layer 1: scalar -> 128 (identical per-entry expression)
  {
    float w = W1[k], b = b1v[k];
#pragma unroll
    for (int q = 0; q < 4; ++q){
      float x = (float)(base + e0 + q) * dt;
      hA[e0 + q][k] = tanhf(fmaf(x, w, b));
    }
  }
  __syncthreads();

  dense4(hA, hB, W2, b2v, k, e0);   // layer 2
  __syncthreads();
  dense4(hB, hA, W3, b3v, k, e0);   // layer 3
  __syncthreads();

  // layer 4: 128 -> 1, softplus. Wave wv owns entries wv*2, wv*2+1;
  // identical expression + xor-tree -> bit-identical table values.
  {
    const int wv   = tid >> 6;       // 0..3
    const int lane = tid & 63;
    float wa = W4[lane], wb = W4[lane + 64];
    float b4s = b4v[0];
#pragma unroll
    for (int r = 0; r < 2; ++r){
      int e = wv * 2 + r;
      float p = hA[e][lane] * wa + hA[e][lane + 64] * wb;
      p += __shfl_xor(p, 32);
      p += __shfl_xor(p, 16);
      p += __shfl_xor(p, 8);
      p += __shfl_xor(p, 4);
      p += __shfl_xor(p, 2);
      p += __shfl_xor(p, 1);
      if (lane == 0) tab[base + e] = softplusf(p + b4s);
    }
  }
}

// ---------- fused: pairs log-sum + MC integral (unchanged from R4) ----------
__global__ __launch_bounds__(F_THREADS) void fused_kernel(
    const float* __restrict__ t,        // [16][384]
    const int* __restrict__ seq_lens,   // [16]
    const float* __restrict__ bg,
    const float* __restrict__ tab,
    float* __restrict__ partials)       // [2*FUSED_BLOCKS]: logs then mc
{
  __shared__ float sm_tab[N_TAB];       // 16 KB
  __shared__ float redL[8], redM[8];

  const int tid  = threadIdx.x;
  const int lane = tid & 63;
  const int wv   = tid >> 6;           // 0..7
  const float bgv = bg[0];

  // stage table to LDS: 4096 floats / 512 threads = 2 float4 each
  {
    const float4* g4 = (const float4*)tab;
    float4* s4 = (float4*)sm_tab;
#pragma unroll
    for (int q = 0; q < 2; ++q)
      s4[q * F_THREADS + tid] = g4[q * F_THREADS + tid];
  }
  __syncthreads();

  float logsum = 0.0f;   // only lane 0 accumulates
  float mcv    = 0.0f;

  // pairs: tasks gwave + kk*2880, kk = 0..2 (task < 6144)
  const int gwave = blockIdx.x * 8 + wv;   // 0..2879
#pragma unroll
  for (int kk = 0; kk < 3; ++kk){
    unsigned task = (unsigned)gwave + (unsigned)kk * 2880u;
    if (task < 6144u){
      unsigned b = task / 384u;
      int i = (int)(task - b * 384u);
      if (i < seq_lens[b]){
        const float* tb = t + b * 384u;
        float ti = tb[i];
        float s = 0.0f;
        for (int j = lane; j < i; j += 64)
          s += TABLE_LDS(ti - tb[j]);
        s += __shfl_xor(s, 32);
        s += __shfl_xor(s, 16);
        s += __shfl_xor(s, 8);
        s += __shfl_xor(s, 4);
        s += __shfl_xor(s, 2);
        s += __shfl_xor(s, 1);
        if (lane == 0) logsum += logf(s + bgv);
      }
    }
  }

  // Monte Carlo sample: value is a function of idx only -> bit-identical
  {
    int idx = blockIdx.x * F_THREADS + tid;
    if (idx < N_MC_TOTAL){
      int l = idx % 384;
      int b = (idx / 384) & 15;
      if (l < seq_lens[b]){
        float tv = t[b * 384 + l];
        float dl = T_END_F - tv;
        float u  = threefry_u01((unsigned)idx);
        mcv = (TABLE_LDS(u * dl) + 1e-10f) * dl;
      }
    }
  }
  mcv += __shfl_xor(mcv, 32);
  mcv += __shfl_xor(mcv, 16);
  mcv += __shfl_xor(mcv, 8);
  mcv += __shfl_xor(mcv, 4);
  mcv += __shfl_xor(mcv, 2);
  mcv += __shfl_xor(mcv, 1);

  if (lane == 0){ redL[wv] = logsum; redM[wv] = mcv; }
  __syncthreads();
  if (tid == 0){
    float bl = 0.0f, bm = 0.0f;
#pragma unroll
    for (int q = 0; q < 8; ++q){ bl += redL[q]; bm += redM[q]; }
    partials[blockIdx.x]                = bl;
    partials[FUSED_BLOCKS + blockIdx.x] = bm;
  }
}

// ---------- finalize: deterministic 16-residue reduction, 1 wave ----------
__global__ __launch_bounds__(64) void finalize_kernel(
    const float* __restrict__ partials,
    const float* __restrict__ bg,
    float* __restrict__ out)
{
  __shared__ float sl16[16], sm16[16];
  const int lane = threadIdx.x;
  if (lane < 16){
    float a = 0.0f, b = 0.0f;
    for (int p = lane; p < FUSED_BLOCKS; p += 16){
      a += partials[p];
      b += partials[FUSED_BLOCKS + p];
    }
    sl16[lane] = a;
    sm16[lane] = b;
  }
  __syncthreads();
  if (lane == 0){
    float sl = 0.0f, sm = 0.0f;
#pragma unroll
    for (int q = 0; q < 16; ++q){ sl += sl16[q]; sm += sm16[q]; }
    float bgv = bg[0];
    float lamb_ints_total = sm * (1.0f / 15.0f) + 16.0f * T_END_F * bgv;
    out[0] = -(sl - lamb_ints_total) / 16.0f;
  }
}

extern "C" void kernel_launch(void* const* d_in, const int* in_sizes, int n_in,
                              void* d_out, int out_size, void* d_ws, size_t ws_size,
                              hipStream_t stream)
{
  const float* seq_pads = (const float*)d_in[0];
  const int*   seq_lens = (const int*)d_in[1];
  const float* bg       = (const float*)d_in[2];
  const float* W1 = (const float*)d_in[3];
  const float* b1 = (const float*)d_in[4];
  const float* W2 = (const float*)d_in[5];
  const float* b2 = (const float*)d_in[6];
  const float* W3 = (const float*)d_in[7];
  const float* b3 = (const float*)d_in[8];
  const float* W4 = (const float*)d_in[9];
  const float* b4 = (const float*)d_in[10];
  float* out = (float*)d_out;

  float* tab      = (float*)d_ws;          // N_TAB floats
  float* partials = tab + N_TAB;           // 2*FUSED_BLOCKS floats

  build_table_kernel<<<NBLK_BUILD, B_THREADS, 0, stream>>>(
      W1, b1, W2, b2, W3, b3, W4, b4, tab);
  fused_kernel<<<FUSED_BLOCKS, F_THREADS, 0, stream>>>(
      seq_pads, seq_lens, bg, tab, partials);
  finalize_kernel<<<1, 64, 0, stream>>>(partials, bg, out);
}

// Round 7
// 101.248 us; speedup vs baseline: 1.7981x; 1.0989x over previous
//
#include <hip/hip_runtime.h>
#include <math.h>

#define T_END_F 100.0f
#define N_TAB 4096
#define HID 128
#define N_MC_TOTAL 92160  // 15 * 16 * 384
#define TF_HALF 46080u

// build: 512 blocks x 256 threads; 8 entries/block, 4 entries/thread
// (weight reuse 4, ILP 4). R4-champion structure; only change vs R4 is the
// j-loop unroll window 4 -> 8 (compiler schedules loads, NOT manual prefetch:
// R5 manual-128 spilled 276MB scratch, R6 manual-64-dbuf lost 14us).
#define B_EV 8
#define B_THREADS 256
#define NBLK_BUILD (N_TAB / B_EV)   // 512

// fused: 360 blocks x 512 threads (unchanged from R4, measured good).
#define FUSED_BLOCKS 360
#define F_THREADS 512

// ---------- math helpers ----------
__device__ __forceinline__ float softplusf(float z){
  return fmaxf(z, 0.0f) + log1pf(expf(-fabsf(z)));
}

__device__ __forceinline__ unsigned rotl32(unsigned x, unsigned d){
  return (x << d) | (x >> (32u - d));
}

// Bit-exact JAX threefry2x32 uniform for key(42), total count 92160.
__device__ float threefry_u01(unsigned idx){
  unsigned i0, i1;
  bool second = idx >= TF_HALF;
  if (second){ i0 = idx - TF_HALF; i1 = idx; }
  else       { i0 = idx;           i1 = idx + TF_HALF; }
  const unsigned ks0 = 0u;
  const unsigned ks1 = 42u;
  const unsigned ks2 = 0x1BD11BDAu ^ ks0 ^ ks1;
  unsigned x0 = i0 + ks0;
  unsigned x1 = i1 + ks1;
#define TF_R(r) { x0 += x1; x1 = rotl32(x1, (r)); x1 ^= x0; }
  TF_R(13) TF_R(15) TF_R(26) TF_R(6)
  x0 += ks1; x1 += ks2 + 1u;
  TF_R(17) TF_R(29) TF_R(16) TF_R(24)
  x0 += ks2; x1 += ks0 + 2u;
  TF_R(13) TF_R(15) TF_R(26) TF_R(6)
  x0 += ks0; x1 += ks1 + 3u;
  TF_R(17) TF_R(29) TF_R(16) TF_R(24)
  x0 += ks1; x1 += ks2 + 4u;
  TF_R(13) TF_R(15) TF_R(26) TF_R(6)
  x0 += ks2; x1 += ks0 + 5u;
#undef TF_R
  unsigned bits = second ? x1 : x0;
  unsigned fb = (bits >> 9) | 0x3F800000u;
  return __uint_as_float(fb) - 1.0f;
}

// LDS-resident table lookup
#define TABLE_LDS(xval) ({                                        \
  float _pos = (xval) * ((float)(N_TAB - 1) / T_END_F);           \
  int _i = (int)_pos;                                             \
  if (_i < 0) _i = 0;                                             \
  if (_i > N_TAB - 2) _i = N_TAB - 2;                             \
  float _fr = _pos - (float)_i;                                   \
  float _a = sm_tab[_i];                                          \
  float _b = sm_tab[_i + 1];                                      \
  fmaf(_fr, _b - _a, _a); })

// dense layer for FOUR entries sharing every weight load (reuse 4, ILP 4).
// Per-(entry,unit) fmaf chain is the same ascending-j single-accumulator
// order as all previous versions -> bit-identical results.
// unroll 8: 32 weight loads in the scheduler's window (2x R4), compiler
// picks hoist depth (manual prefetch variants R5/R6 both regressed).
__device__ __forceinline__ void dense4(
    const float (*__restrict__ hin)[HID], float (*__restrict__ hout)[HID],
    const float* __restrict__ W, const float* __restrict__ bv,
    int k, int e0)
{
  float acc0 = bv[k];
  float acc1 = acc0, acc2 = acc0, acc3 = acc0;
#pragma unroll 8
  for (int j = 0; j < HID; j += 4){
    float w0 = W[(j+0)*HID + k];
    float w1 = W[(j+1)*HID + k];
    float w2 = W[(j+2)*HID + k];
    float w3 = W[(j+3)*HID + k];
    float4 h0 = *(const float4*)&hin[e0 + 0][j];   // wave-uniform LDS broadcast
    float4 h1 = *(const float4*)&hin[e0 + 1][j];
    float4 h2 = *(const float4*)&hin[e0 + 2][j];
    float4 h3 = *(const float4*)&hin[e0 + 3][j];
    acc0 = fmaf(h0.x, w0, acc0);  acc1 = fmaf(h1.x, w0, acc1);
    acc2 = fmaf(h2.x, w0, acc2);  acc3 = fmaf(h3.x, w0, acc3);
    acc0 = fmaf(h0.y, w1, acc0);  acc1 = fmaf(h1.y, w1, acc1);
    acc2 = fmaf(h2.y, w1, acc2);  acc3 = fmaf(h3.y, w1, acc3);
    acc0 = fmaf(h0.z, w2, acc0);  acc1 = fmaf(h1.z, w2, acc1);
    acc2 = fmaf(h2.z, w2, acc2);  acc3 = fmaf(h3.z, w2, acc3);
    acc0 = fmaf(h0.w, w3, acc0);  acc1 = fmaf(h1.w, w3, acc1);
    acc2 = fmaf(h2.w, w3, acc2);  acc3 = fmaf(h3.w, w3, acc3);
  }
  hout[e0 + 0][k] = tanhf(acc0);
  hout[e0 + 1][k] = tanhf(acc1);
  hout[e0 + 2][k] = tanhf(acc2);
  hout[e0 + 3][k] = tanhf(acc3);
}

// ---------- table build: 512 blocks x 256 threads ----------
__global__ __launch_bounds__(B_THREADS) void build_table_kernel(
    const float* __restrict__ W1, const float* __restrict__ b1v,
    const float* __restrict__ W2, const float* __restrict__ b2v,
    const float* __restrict__ W3, const float* __restrict__ b3v,
    const float* __restrict__ W4, const float* __restrict__ b4v,
    float* __restrict__ tab)
{
  __shared__ float hA[B_EV][HID];   // 4 KB
  __shared__ float hB[B_EV][HID];   // 4 KB
  const int tid = threadIdx.x;
  const int k   = tid & 127;       // hidden unit
  const int g   = tid >> 7;        // 0/1: which 4-entry group
  const int e0  = g * 4;
  const int base = blockIdx.x * B_EV;
  const float dt = T_END_F / (float)(N_TAB - 1);

  // layer 1: scalar -> 128 (identical per-entry expression)
  {
    float w = W1[k], b = b1v[k];
#pragma unroll
    for (int q = 0; q < 4; ++q){
      float x = (float)(base + e0 + q) * dt;
      hA[e0 + q][k] = tanhf(fmaf(x, w, b));
    }
  }
  __syncthreads();

  dense4(hA, hB, W2, b2v, k, e0);   // layer 2
  __syncthreads();
  dense4(hB, hA, W3, b3v, k, e0);   // layer 3
  __syncthreads();

  // layer 4: 128 -> 1, softplus. Wave wv owns entries wv*2, wv*2+1;
  // identical expression + xor-tree -> bit-identical table values.
  {
    const int wv   = tid >> 6;       // 0..3
    const int lane = tid & 63;
    float wa = W4[lane], wb = W4[lane + 64];
    float b4s = b4v[0];
#pragma unroll
    for (int r = 0; r < 2; ++r){
      int e = wv * 2 + r;
      float p = hA[e][lane] * wa + hA[e][lane + 64] * wb;
      p += __shfl_xor(p, 32);
      p += __shfl_xor(p, 16);
      p += __shfl_xor(p, 8);
      p += __shfl_xor(p, 4);
      p += __shfl_xor(p, 2);
      p += __shfl_xor(p, 1);
      if (lane == 0) tab[base + e] = softplusf(p + b4s);
    }
  }
}

// ---------- fused: pairs log-sum + MC integral (unchanged from R4) ----------
__global__ __launch_bounds__(F_THREADS) void fused_kernel(
    const float* __restrict__ t,        // [16][384]
    const int* __restrict__ seq_lens,   // [16]
    const float* __restrict__ bg,
    const float* __restrict__ tab,
    float* __restrict__ partials)       // [2*FUSED_BLOCKS]: logs then mc
{
  __shared__ float sm_tab[N_TAB];       // 16 KB
  __shared__ float redL[8], redM[8];

  const int tid  = threadIdx.x;
  const int lane = tid & 63;
  const int wv   = tid >> 6;           // 0..7
  const float bgv = bg[0];

  // stage table to LDS: 4096 floats / 512 threads = 2 float4 each
  {
    const float4* g4 = (const float4*)tab;
    float4* s4 = (float4*)sm_tab;
#pragma unroll
    for (int q = 0; q < 2; ++q)
      s4[q * F_THREADS + tid] = g4[q * F_THREADS + tid];
  }
  __syncthreads();

  float logsum = 0.0f;   // only lane 0 accumulates
  float mcv    = 0.0f;

  // pairs: tasks gwave + kk*2880, kk = 0..2 (task < 6144)
  const int gwave = blockIdx.x * 8 + wv;   // 0..2879
#pragma unroll
  for (int kk = 0; kk < 3; ++kk){
    unsigned task = (unsigned)gwave + (unsigned)kk * 2880u;
    if (task < 6144u){
      unsigned b = task / 384u;
      int i = (int)(task - b * 384u);
      if (i < seq_lens[b]){
        const float* tb = t + b * 384u;
        float ti = tb[i];
        float s = 0.0f;
        for (int j = lane; j < i; j += 64)
          s += TABLE_LDS(ti - tb[j]);
        s += __shfl_xor(s, 32);
        s += __shfl_xor(s, 16);
        s += __shfl_xor(s, 8);
        s += __shfl_xor(s, 4);
        s += __shfl_xor(s, 2);
        s += __shfl_xor(s, 1);
        if (lane == 0) logsum += logf(s + bgv);
      }
    }
  }

  // Monte Carlo sample: value is a function of idx only -> bit-identical
  {
    int idx = blockIdx.x * F_THREADS + tid;
    if (idx < N_MC_TOTAL){
      int l = idx % 384;
      int b = (idx / 384) & 15;
      if (l < seq_lens[b]){
        float tv = t[b * 384 + l];
        float dl = T_END_F - tv;
        float u  = threefry_u01((unsigned)idx);
        mcv = (TABLE_LDS(u * dl) + 1e-10f) * dl;
      }
    }
  }
  mcv += __shfl_xor(mcv, 32);
  mcv += __shfl_xor(mcv, 16);
  mcv += __shfl_xor(mcv, 8);
  mcv += __shfl_xor(mcv, 4);
  mcv += __shfl_xor(mcv, 2);
  mcv += __shfl_xor(mcv, 1);

  if (lane == 0){ redL[wv] = logsum; redM[wv] = mcv; }
  __syncthreads();
  if (tid == 0){
    float bl = 0.0f, bm = 0.0f;
#pragma unroll
    for (int q = 0; q < 8; ++q){ bl += redL[q]; bm += redM[q]; }
    partials[blockIdx.x]                = bl;
    partials[FUSED_BLOCKS + blockIdx.x] = bm;
  }
}

// ---------- finalize: deterministic 16-residue reduction, 1 wave ----------
__global__ __launch_bounds__(64) void finalize_kernel(
    const float* __restrict__ partials,
    const float* __restrict__ bg,
    float* __restrict__ out)
{
  __shared__ float sl16[16], sm16[16];
  const int lane = threadIdx.x;
  if (lane < 16){
    float a = 0.0f, b = 0.0f;
    for (int p = lane; p < FUSED_BLOCKS; p += 16){
      a += partials[p];
      b += partials[FUSED_BLOCKS + p];
    }
    sl16[lane] = a;
    sm16[lane] = b;
  }
  __syncthreads();
  if (lane == 0){
    float sl = 0.0f, sm = 0.0f;
#pragma unroll
    for (int q = 0; q < 16; ++q){ sl += sl16[q]; sm += sm16[q]; }
    float bgv = bg[0];
    float lamb_ints_total = sm * (1.0f / 15.0f) + 16.0f * T_END_F * bgv;
    out[0] = -(sl - lamb_ints_total) / 16.0f;
  }
}

extern "C" void kernel_launch(void* const* d_in, const int* in_sizes, int n_in,
                              void* d_out, int out_size, void* d_ws, size_t ws_size,
                              hipStream_t stream)
{
  const float* seq_pads = (const float*)d_in[0];
  const int*   seq_lens = (const int*)d_in[1];
  const float* bg       = (const float*)d_in[2];
  const float* W1 = (const float*)d_in[3];
  const float* b1 = (const float*)d_in[4];
  const float* W2 = (const float*)d_in[5];
  const float* b2 = (const float*)d_in[6];
  const float* W3 = (const float*)d_in[7];
  const float* b3 = (const float*)d_in[8];
  const float* W4 = (const float*)d_in[9];
  const float* b4 = (const float*)d_in[10];
  float* out = (float*)d_out;

  float* tab      = (float*)d_ws;          // N_TAB floats
  float* partials = tab + N_TAB;           // 2*FUSED_BLOCKS floats

  build_table_kernel<<<NBLK_BUILD, B_THREADS, 0, stream>>>(
      W1, b1, W2, b2, W3, b3, W4, b4, tab);
  fused_kernel<<<FUSED_BLOCKS, F_THREADS, 0, stream>>>(
      seq_pads, seq_lens, bg, tab, partials);
  finalize_kernel<<<1, 64, 0, stream>>>(partials, bg, out);
}

// Round 10
// 96.645 us; speedup vs baseline: 1.8837x; 1.0476x over previous
//
#include <hip/hip_runtime.h>
#include <math.h>

#define T_END_F 100.0f
#define N_TAB 4096
#define HID 128
#define N_MC_TOTAL 92160  // 15 * 16 * 384
#define TF_HALF 46080u

// build: 512 blocks x 256 threads; 8 entries/block, 4 entries/thread
// (weight reuse 4, ILP 4). 2048 waves = 8 waves/CU.
// R4 session champion — passed 4x, 97.0 us. Do not perturb:
//   R5 (128-reg column) spilled -> 276 MB scratch, 182 us
//   R6 (manual 64-reg dbuf prefetch) -> 111 us
//   R7 (unroll 8) -> 101 us (neutral/worse)
//   R8/R9 (folded ticket finalize) -> absmax 5888 (out never written;
//     ticket cnt visibility issue under the 2-kernel fold, unresolved)
#define B_EV 8
#define B_THREADS 256
#define NBLK_BUILD (N_TAB / B_EV)   // 512

// fused: 360 blocks x 512 threads = 2880 waves. MC thread-per-sample,
// <=3 pair tasks/wave. Plain per-block partial stores to distinct
// addresses; separate 1-wave finalize kernel reduces them (stream-order
// kernel-boundary visibility — the only verified cross-dispatch handoff).
#define FUSED_BLOCKS 360
#define F_THREADS 512

// ---------- math helpers ----------
__device__ __forceinline__ float softplusf(float z){
  return fmaxf(z, 0.0f) + log1pf(expf(-fabsf(z)));
}

__device__ __forceinline__ unsigned rotl32(unsigned x, unsigned d){
  return (x << d) | (x >> (32u - d));
}

// Bit-exact JAX threefry2x32 uniform for key(42), total count 92160.
__device__ float threefry_u01(unsigned idx){
  unsigned i0, i1;
  bool second = idx >= TF_HALF;
  if (second){ i0 = idx - TF_HALF; i1 = idx; }
  else       { i0 = idx;           i1 = idx + TF_HALF; }
  const unsigned ks0 = 0u;
  const unsigned ks1 = 42u;
  const unsigned ks2 = 0x1BD11BDAu ^ ks0 ^ ks1;
  unsigned x0 = i0 + ks0;
  unsigned x1 = i1 + ks1;
#define TF_R(r) { x0 += x1; x1 = rotl32(x1, (r)); x1 ^= x0; }
  TF_R(13) TF_R(15) TF_R(26) TF_R(6)
  x0 += ks1; x1 += ks2 + 1u;
  TF_R(17) TF_R(29) TF_R(16) TF_R(24)
  x0 += ks2; x1 += ks0 + 2u;
  TF_R(13) TF_R(15) TF_R(26) TF_R(6)
  x0 += ks0; x1 += ks1 + 3u;
  TF_R(17) TF_R(29) TF_R(16) TF_R(24)
  x0 += ks1; x1 += ks2 + 4u;
  TF_R(13) TF_R(15) TF_R(26) TF_R(6)
  x0 += ks2; x1 += ks0 + 5u;
#undef TF_R
  unsigned bits = second ? x1 : x0;
  unsigned fb = (bits >> 9) | 0x3F800000u;
  return __uint_as_float(fb) - 1.0f;
}

// LDS-resident table lookup
#define TABLE_LDS(xval) ({                                        \
  float _pos = (xval) * ((float)(N_TAB - 1) / T_END_F);           \
  int _i = (int)_pos;                                             \
  if (_i < 0) _i = 0;                                             \
  if (_i > N_TAB - 2) _i = N_TAB - 2;                             \
  float _fr = _pos - (float)_i;                                   \
  float _a = sm_tab[_i];                                          \
  float _b = sm_tab[_i + 1];                                      \
  fmaf(_fr, _b - _a, _a); })

// dense layer for FOUR entries sharing every weight load (reuse 4, ILP 4).
// Per-(entry,unit) fmaf chain is the same ascending-j single-accumulator
// order as all previous versions -> bit-identical results.
__device__ __forceinline__ void dense4(
    const float (*__restrict__ hin)[HID], float (*__restrict__ hout)[HID],
    const float* __restrict__ W, const float* __restrict__ bv,
    int k, int e0)
{
  float acc0 = bv[k];
  float acc1 = acc0, acc2 = acc0, acc3 = acc0;
#pragma unroll 4
  for (int j = 0; j < HID; j += 4){
    float w0 = W[(j+0)*HID + k];
    float w1 = W[(j+1)*HID + k];
    float w2 = W[(j+2)*HID + k];
    float w3 = W[(j+3)*HID + k];
    float4 h0 = *(const float4*)&hin[e0 + 0][j];   // wave-uniform LDS broadcast
    float4 h1 = *(const float4*)&hin[e0 + 1][j];
    float4 h2 = *(const float4*)&hin[e0 + 2][j];
    float4 h3 = *(const float4*)&hin[e0 + 3][j];
    acc0 = fmaf(h0.x, w0, acc0);  acc1 = fmaf(h1.x, w0, acc1);
    acc2 = fmaf(h2.x, w0, acc2);  acc3 = fmaf(h3.x, w0, acc3);
    acc0 = fmaf(h0.y, w1, acc0);  acc1 = fmaf(h1.y, w1, acc1);
    acc2 = fmaf(h2.y, w1, acc2);  acc3 = fmaf(h3.y, w1, acc3);
    acc0 = fmaf(h0.z, w2, acc0);  acc1 = fmaf(h1.z, w2, acc1);
    acc2 = fmaf(h2.z, w2, acc2);  acc3 = fmaf(h3.z, w2, acc3);
    acc0 = fmaf(h0.w, w3, acc0);  acc1 = fmaf(h1.w, w3, acc1);
    acc2 = fmaf(h2.w, w3, acc2);  acc3 = fmaf(h3.w, w3, acc3);
  }
  hout[e0 + 0][k] = tanhf(acc0);
  hout[e0 + 1][k] = tanhf(acc1);
  hout[e0 + 2][k] = tanhf(acc2);
  hout[e0 + 3][k] = tanhf(acc3);
}

// ---------- table build: 512 blocks x 256 threads ----------
__global__ __launch_bounds__(B_THREADS) void build_table_kernel(
    const float* __restrict__ W1, const float* __restrict__ b1v,
    const float* __restrict__ W2, const float* __restrict__ b2v,
    const float* __restrict__ W3, const float* __restrict__ b3v,
    const float* __restrict__ W4, const float* __restrict__ b4v,
    float* __restrict__ tab)
{
  __shared__ float hA[B_EV][HID];   // 4 KB
  __shared__ float hB[B_EV][HID];   // 4 KB
  const int tid = threadIdx.x;
  const int k   = tid & 127;       // hidden unit
  const int g   = tid >> 7;        // 0/1: which 4-entry group
  const int e0  = g * 4;
  const int base = blockIdx.x * B_EV;
  const float dt = T_END_F / (float)(N_TAB - 1);

  // layer 1: scalar -> 128 (identical per-entry expression)
  {
    float w = W1[k], b = b1v[k];
#pragma unroll
    for (int q = 0; q < 4; ++q){
      float x = (float)(base + e0 + q) * dt;
      hA[e0 + q][k] = tanhf(fmaf(x, w, b));
    }
  }
  __syncthreads();

  dense4(hA, hB, W2, b2v, k, e0);   // layer 2
  __syncthreads();
  dense4(hB, hA, W3, b3v, k, e0);   // layer 3
  __syncthreads();

  // layer 4: 128 -> 1, softplus. Wave wv owns entries wv*2, wv*2+1;
  // identical expression + xor-tree -> bit-identical table values.
  {
    const int wv   = tid >> 6;       // 0..3
    const int lane = tid & 63;
    float wa = W4[lane], wb = W4[lane + 64];
    float b4s = b4v[0];
#pragma unroll
    for (int r = 0; r < 2; ++r){
      int e = wv * 2 + r;
      float p = hA[e][lane] * wa + hA[e][lane + 64] * wb;
      p += __shfl_xor(p, 32);
      p += __shfl_xor(p, 16);
      p += __shfl_xor(p, 8);
      p += __shfl_xor(p, 4);
      p += __shfl_xor(p, 2);
      p += __shfl_xor(p, 1);
      if (lane == 0) tab[base + e] = softplusf(p + b4s);
    }
  }
}

// ---------- fused: pairs log-sum + MC integral ----------
__global__ __launch_bounds__(F_THREADS) void fused_kernel(
    const float* __restrict__ t,        // [16][384]
    const int* __restrict__ seq_lens,   // [16]
    const float* __restrict__ bg,
    const float* __restrict__ tab,
    float* __restrict__ partials)       // [2*FUSED_BLOCKS]: logs then mc
{
  __shared__ float sm_tab[N_TAB];       // 16 KB
  __shared__ float redL[8], redM[8];

  const int tid  = threadIdx.x;
  const int lane = tid & 63;
  const int wv   = tid >> 6;           // 0..7
  const float bgv = bg[0];

  // stage table to LDS: 4096 floats / 512 threads = 2 float4 each
  {
    const float4* g4 = (const float4*)tab;
    float4* s4 = (float4*)sm_tab;
#pragma unroll
    for (int q = 0; q < 2; ++q)
      s4[q * F_THREADS + tid] = g4[q * F_THREADS + tid];
  }
  __syncthreads();

  float logsum = 0.0f;   // only lane 0 accumulates
  float mcv    = 0.0f;

  // pairs: tasks gwave + kk*2880, kk = 0..2 (task < 6144)
  const int gwave = blockIdx.x * 8 + wv;   // 0..2879
#pragma unroll
  for (int kk = 0; kk < 3; ++kk){
    unsigned task = (unsigned)gwave + (unsigned)kk * 2880u;
    if (task < 6144u){
      unsigned b = task / 384u;
      int i = (int)(task - b * 384u);
      if (i < seq_lens[b]){
        const float* tb = t + b * 384u;
        float ti = tb[i];
        float s = 0.0f;
        for (int j = lane; j < i; j += 64)
          s += TABLE_LDS(ti - tb[j]);
        s += __shfl_xor(s, 32);
        s += __shfl_xor(s, 16);
        s += __shfl_xor(s, 8);
        s += __shfl_xor(s, 4);
        s += __shfl_xor(s, 2);
        s += __shfl_xor(s, 1);
        if (lane == 0) logsum += logf(s + bgv);
      }
    }
  }

  // Monte Carlo sample: value is a function of idx only -> bit-identical
  {
    int idx = blockIdx.x * F_THREADS + tid;
    if (idx < N_MC_TOTAL){
      int l = idx % 384;
      int b = (idx / 384) & 15;
      if (l < seq_lens[b]){
        float tv = t[b * 384 + l];
        float dl = T_END_F - tv;
        float u  = threefry_u01((unsigned)idx);
        mcv = (TABLE_LDS(u * dl) + 1e-10f) * dl;
      }
    }
  }
  mcv += __shfl_xor(mcv, 32);
  mcv += __shfl_xor(mcv, 16);
  mcv += __shfl_xor(mcv, 8);
  mcv += __shfl_xor(mcv, 4);
  mcv += __shfl_xor(mcv, 2);
  mcv += __shfl_xor(mcv, 1);

  if (lane == 0){ redL[wv] = logsum; redM[wv] = mcv; }
  __syncthreads();
  if (tid == 0){
    float bl = 0.0f, bm = 0.0f;
#pragma unroll
    for (int q = 0; q < 8; ++q){ bl += redL[q]; bm += redM[q]; }
    partials[blockIdx.x]                = bl;
    partials[FUSED_BLOCKS + blockIdx.x] = bm;
  }
}

// ---------- finalize: deterministic 16-residue reduction, 1 wave ----------
__global__ __launch_bounds__(64) void finalize_kernel(
    const float* __restrict__ partials,
    const float* __restrict__ bg,
    float* __restrict__ out)
{
  __shared__ float sl16[16], sm16[16];
  const int lane = threadIdx.x;
  if (lane < 16){
    float a = 0.0f, b = 0.0f;
    for (int p = lane; p < FUSED_BLOCKS; p += 16){
      a += partials[p];
      b += partials[FUSED_BLOCKS + p];
    }
    sl16[lane] = a;
    sm16[lane] = b;
  }
  __syncthreads();
  if (lane == 0){
    float sl = 0.0f, sm = 0.0f;
#pragma unroll
    for (int q = 0; q < 16; ++q){ sl += sl16[q]; sm += sm16[q]; }
    float bgv = bg[0];
    float lamb_ints_total = sm * (1.0f / 15.0f) + 16.0f * T_END_F * bgv;
    out[0] = -(sl - lamb_ints_total) / 16.0f;
  }
}

extern "C" void kernel_launch(void* const* d_in, const int* in_sizes, int n_in,
                              void* d_out, int out_size, void* d_ws, size_t ws_size,
                              hipStream_t stream)
{
  const float* seq_pads = (const float*)d_in[0];
  const int*   seq_lens = (const int*)d_in[1];
  const float* bg       = (const float*)d_in[2];
  const float* W1 = (const float*)d_in[3];
  const float* b1 = (const float*)d_in[4];
  const float* W2 = (const float*)d_in[5];
  const float* b2 = (const float*)d_in[6];
  const float* W3 = (const float*)d_in[7];
  const float* b3 = (const float*)d_in[8];
  const float* W4 = (const float*)d_in[9];
  const float* b4 = (const float*)d_in[10];
  float* out = (float*)d_out;

  float* tab      = (float*)d_ws;          // N_TAB floats
  float* partials = tab + N_TAB;           // 2*FUSED_BLOCKS floats

  build_table_kernel<<<NBLK_BUILD, B_THREADS, 0, stream>>>(
      W1, b1, W2, b2, W3, b3, W4, b4, tab);
  fused_kernel<<<FUSED_BLOCKS, F_THREADS, 0, stream>>>(
      seq_pads, seq_lens, bg, tab, partials);
  finalize_kernel<<<1, 64, 0, stream>>>(partials, bg, out);
}